// Round 7
// baseline (17725.545 us; speedup 1.0000x reference)
//
#include <hip/hip_runtime.h>
#include <math.h>

#define N_GRID 65160
#define N_MESH 40962
#define N_TOT  106122
#define NE     521280
#define IN_CH  96
#define HID    256
#define OUT_CH 96

// ---------------- concat + transpose: (96,N) channel-major -> (N,96) node-major ----------------
__global__ void k_concat_transpose(const float* __restrict__ xg, const float* __restrict__ xm,
                                   float* __restrict__ h) {
  __shared__ float tile[IN_CH][65];
  int base = blockIdx.x * 64;
  int t = threadIdx.x;
#pragma unroll
  for (int it = 0; it < 24; ++it) {
    int lin = t + it * 256;            // 0..6143 over 96x64
    int c  = lin >> 6;
    int n0 = lin & 63;
    int n = base + n0;
    float v = 0.f;
    if (n < N_TOT) {
      v = (n < N_GRID) ? xg[(size_t)c * N_GRID + n]
                       : xm[(size_t)c * N_MESH + (n - N_GRID)];
    }
    tile[c][n0] = v;
  }
  __syncthreads();
#pragma unroll
  for (int it = 0; it < 24; ++it) {
    int lin = t + it * 256;
    int c  = lin % 96;
    int n0 = lin / 96;
    int n = base + n0;
    if (n < N_TOT) h[(size_t)n * IN_CH + c] = tile[c][n0];
  }
}

// ---------------- CSR build ----------------
__global__ void k_zeroi(int* __restrict__ p, int n) {
  int i = blockIdx.x * 256 + threadIdx.x;
  if (i < n) p[i] = 0;
}
__global__ void k_seti(int* __restrict__ p, int v) { *p = v; }

__global__ void k_hist(const int* __restrict__ dst, int* __restrict__ deg) {
  int e = blockIdx.x * 256 + threadIdx.x;
  if (e < NE) atomicAdd(&deg[dst[e]], 1);
}

__global__ void k_blocksum(const int* __restrict__ deg, int* __restrict__ bsum, int n) {
  __shared__ int s[256];
  int i = blockIdx.x * 256 + threadIdx.x;
  s[threadIdx.x] = (i < n) ? deg[i] : 0;
  __syncthreads();
  for (int st = 128; st > 0; st >>= 1) {
    if (threadIdx.x < st) s[threadIdx.x] += s[threadIdx.x + st];
    __syncthreads();
  }
  if (threadIdx.x == 0) bsum[blockIdx.x] = s[0];
}

__global__ void k_scanbsum(int* __restrict__ bsum, int nb) {   // single block, 512 thr
  __shared__ int s[512];
  int t = threadIdx.x;
  int v = (t < nb) ? bsum[t] : 0;
  s[t] = v;
  __syncthreads();
  for (int off = 1; off < 512; off <<= 1) {
    int x = (t >= off) ? s[t - off] : 0;
    __syncthreads();
    s[t] += x;
    __syncthreads();
  }
  if (t < nb) bsum[t] = s[t] - v;   // exclusive
}

__global__ void k_offsets(const int* __restrict__ deg, const int* __restrict__ bsum,
                          int* __restrict__ off, int* __restrict__ cur, int n) {
  __shared__ int s[256];
  int i = blockIdx.x * 256 + threadIdx.x;
  int v = (i < n) ? deg[i] : 0;
  s[threadIdx.x] = v;
  __syncthreads();
  for (int o = 1; o < 256; o <<= 1) {
    int x = (threadIdx.x >= o) ? s[threadIdx.x - o] : 0;
    __syncthreads();
    s[threadIdx.x] += x;
    __syncthreads();
  }
  if (i < n) {
    int e = bsum[blockIdx.x] + s[threadIdx.x] - v;
    off[i] = e;
    cur[i] = e;
  }
}

__global__ void k_fillcsr(const int* __restrict__ src, const int* __restrict__ dst,
                          int* __restrict__ cur, int* __restrict__ csrc) {
  int e = blockIdx.x * 256 + threadIdx.x;
  if (e < NE) {
    int p = atomicAdd(&cur[dst[e]], 1);
    csrc[p] = src[e];
  }
}

__global__ void k_dinv(const int* __restrict__ deg, float* __restrict__ dinv, int n) {
  int i = blockIdx.x * 256 + threadIdx.x;
  if (i < n) dinv[i] = rsqrtf(1.0f + (float)deg[i]);
}

// ---------------- gather aggregation (no atomics), 2-edge unrolled for MLP ----------------
__global__ void k_gather96(const int* __restrict__ off, const int* __restrict__ csrc,
                           const float* __restrict__ dinv, const float* __restrict__ h,
                           float* __restrict__ agg) {
  int i = blockIdx.x * 256 + threadIdx.x;
  if (i >= N_TOT * 24) return;
  int n = i / 24;
  int c4 = (i % 24) << 2;
  float di = dinv[n];
  float4 v = *(const float4*)(h + (size_t)n * 96 + c4);
  float w0 = di * di;
  float4 acc = make_float4(v.x * w0, v.y * w0, v.z * w0, v.w * w0);
  int e0 = off[n], e1 = off[n + 1];
  int e = e0;
  for (; e + 1 < e1; e += 2) {
    int s0 = csrc[e], s1 = csrc[e + 1];
    float wa = dinv[s0] * di, wb = dinv[s1] * di;
    float4 u0 = *(const float4*)(h + (size_t)s0 * 96 + c4);
    float4 u1 = *(const float4*)(h + (size_t)s1 * 96 + c4);
    acc.x += u0.x * wa + u1.x * wb;
    acc.y += u0.y * wa + u1.y * wb;
    acc.z += u0.z * wa + u1.z * wb;
    acc.w += u0.w * wa + u1.w * wb;
  }
  if (e < e1) {
    int s = csrc[e];
    float w = dinv[s] * di;
    float4 u = *(const float4*)(h + (size_t)s * 96 + c4);
    acc.x += u.x * w; acc.y += u.y * w; acc.z += u.z * w; acc.w += u.w * w;
  }
  *(float4*)(agg + (size_t)n * 96 + c4) = acc;
}

__global__ void k_gather256(const int* __restrict__ off, const int* __restrict__ csrc,
                            const float* __restrict__ dinv, const float* __restrict__ h1,
                            float* __restrict__ agg) {
  int i = blockIdx.x * 256 + threadIdx.x;
  if (i >= N_GRID * 64) return;
  int n = i >> 6;
  int c4 = (i & 63) << 2;
  float di = dinv[n];
  float4 v = *(const float4*)(h1 + (size_t)n * 256 + c4);
  float w0 = di * di;
  float4 acc = make_float4(v.x * w0, v.y * w0, v.z * w0, v.w * w0);
  int e0 = off[n], e1 = off[n + 1];
  int e = e0;
  for (; e + 1 < e1; e += 2) {
    int s0 = csrc[e], s1 = csrc[e + 1];
    float wa = dinv[s0] * di, wb = dinv[s1] * di;
    float4 u0 = *(const float4*)(h1 + (size_t)s0 * 256 + c4);
    float4 u1 = *(const float4*)(h1 + (size_t)s1 * 256 + c4);
    acc.x += u0.x * wa + u1.x * wb;
    acc.y += u0.y * wa + u1.y * wb;
    acc.z += u0.z * wa + u1.z * wb;
    acc.w += u0.w * wa + u1.w * wb;
  }
  if (e < e1) {
    int s = csrc[e];
    float w = dinv[s] * di;
    float4 u = *(const float4*)(h1 + (size_t)s * 256 + c4);
    acc.x += u.x * w; acc.y += u.y * w; acc.z += u.z * w; acc.w += u.w * w;
  }
  *(float4*)(agg + (size_t)n * 256 + c4) = acc;
}

// ---------------- fp32 tiled GEMM: compile-time K, BK=32, LDS double-buffer (1 barrier/K-tile),
// A-prefetch issued before compute, W after (L2-hot). Conflict-free LDS reads.
// __launch_bounds__(256, 1): VGPR cap 256. Natural demand ~145 (acc64+frag16+prefetch32+addr).
// Round 6's (256,2) capped at 128 -> accumulator spill -> 13 GB scratch FETCH, 7.3 ms. Round 4's
// (256,5) capped at 51 -> same. At ~150 VGPR occupancy bin is 8 waves/CU = 2 blocks/CU, which
// equals the LDS limit (2x66.8 KB = 134 KB of 160) — so the relaxed cap costs NO residency.
template<int K, int ACT, bool TRANSC, bool BIAS>
__global__ __launch_bounds__(256, 1) void k_gemm(const float* __restrict__ A, const float* __restrict__ W,
                                                 const float* __restrict__ bias, float* __restrict__ C,
                                                 int M, int N, int ldc) {
  constexpr int BM = 128, BN = 128, BK = 32, NIT = K / BK;
  __shared__ float As[2][BK][BM + 1];   // 2 x 16.5 KB
  __shared__ float Ws[2][BK][BN + 4];   // 2 x 16.9 KB  -> 66.8 KB total, 2 blocks/CU
  int t = threadIdx.x;
  int tx = t & 15, ty = t >> 4;
  int bm = blockIdx.y * BM, bn = blockIdx.x * BN;

  float4 pa[4], pw[4];
  auto loadA = [&](int it) {
#pragma unroll
    for (int q = 0; q < 4; ++q) {
      int idx = t + q * 256;                 // 0..1023 over 128 rows x 8 k4-groups
      int m = idx >> 3, k4 = (idx & 7) << 2;
      pa[q] = make_float4(0.f, 0.f, 0.f, 0.f);
      if (bm + m < M) pa[q] = *(const float4*)(A + (size_t)(bm + m) * K + it * BK + k4);
    }
  };
  auto loadW = [&](int it) {
#pragma unroll
    for (int q = 0; q < 4; ++q) {
      int idx = t + q * 256;                 // 0..1023 over 32 k x 32 j4-groups
      int k = idx >> 5, j4 = (idx & 31) << 2;
      pw[q] = make_float4(0.f, 0.f, 0.f, 0.f);
      if (bn + j4 + 3 < N) pw[q] = *(const float4*)(W + (size_t)(it * BK + k) * N + bn + j4);
    }
  };
  auto store = [&](int b) {
#pragma unroll
    for (int q = 0; q < 4; ++q) {
      int idx = t + q * 256;
      int m = idx >> 3, k4 = (idx & 7) << 2;
      As[b][k4 + 0][m] = pa[q].x;
      As[b][k4 + 1][m] = pa[q].y;
      As[b][k4 + 2][m] = pa[q].z;
      As[b][k4 + 3][m] = pa[q].w;
      int k = idx >> 5, j4 = (idx & 31) << 2;
      *(float4*)&Ws[b][k][j4] = pw[q];
    }
  };

  float acc[8][8] = {};
  loadA(0); loadW(0); store(0);
#pragma unroll
  for (int it = 0; it < NIT; ++it) {
    __syncthreads();                          // buf[it&1] ready; all waves done with buf[(it+1)&1]
    if (it + 1 < NIT) loadA(it + 1);          // issue HBM loads early; waited in store()
    int b = it & 1;
#pragma unroll
    for (int k = 0; k < BK; ++k) {
      float a[8], w[8];
      *(float4*)&a[0] = *(const float4*)&As[b][k][ty * 4];
      *(float4*)&a[4] = *(const float4*)&As[b][k][64 + ty * 4];
      *(float4*)&w[0] = *(const float4*)&Ws[b][k][tx * 4];
      *(float4*)&w[4] = *(const float4*)&Ws[b][k][64 + tx * 4];
#pragma unroll
      for (int i = 0; i < 8; ++i)
#pragma unroll
        for (int j = 0; j < 8; ++j)
          acc[i][j] += a[i] * w[j];
    }
    if (it + 1 < NIT) { loadW(it + 1); store((it + 1) & 1); }
  }
  if (!TRANSC) {
#pragma unroll
    for (int i = 0; i < 8; ++i) {
      int gm = bm + ((i < 4) ? ty * 4 + i : 64 + ty * 4 + (i - 4));
      if (gm >= M) continue;
      float v[8];
#pragma unroll
      for (int j = 0; j < 8; ++j) {
        int gj = bn + ((j < 4) ? tx * 4 + j : 64 + tx * 4 + (j - 4));
        float x = acc[i][j];
        if (BIAS && gj < N) x += bias[gj];
        if (ACT) x = 0.5f * x * (1.0f + erff(x * 0.70710678118654752f));
        v[j] = x;
      }
      int c0 = bn + tx * 4, c1 = bn + 64 + tx * 4;
      float* row = C + (size_t)gm * ldc;
      if (c0 + 3 < N) *(float4*)(row + c0) = make_float4(v[0], v[1], v[2], v[3]);
      else { for (int j = 0; j < 4; ++j) if (c0 + j < N) row[c0 + j] = v[j]; }
      if (c1 + 3 < N) *(float4*)(row + c1) = make_float4(v[4], v[5], v[6], v[7]);
      else { for (int j = 0; j < 4; ++j) if (c1 + j < N) row[c1 + j] = v[4 + j]; }
    }
  } else {
#pragma unroll
    for (int j = 0; j < 8; ++j) {
      int gj = bn + ((j < 4) ? tx * 4 + j : 64 + tx * 4 + (j - 4));
      if (gj >= N) continue;
      float b = BIAS ? bias[gj] : 0.f;
      float v[8];
#pragma unroll
      for (int i = 0; i < 8; ++i) {
        float x = acc[i][j] + b;
        if (ACT) x = 0.5f * x * (1.0f + erff(x * 0.70710678118654752f));
        v[i] = x;
      }
      int r0 = bm + ty * 4, r1 = bm + 64 + ty * 4;
      float* col = C + (size_t)gj * ldc;
      if (r0 + 3 < M) *(float4*)(col + r0) = make_float4(v[0], v[1], v[2], v[3]);
      else { for (int i = 0; i < 4; ++i) if (r0 + i < M) col[r0 + i] = v[i]; }
      if (r1 + 3 < M) *(float4*)(col + r1) = make_float4(v[4], v[5], v[6], v[7]);
      else { for (int i = 0; i < 4; ++i) if (r1 + i < M) col[r1 + i] = v[4 + i]; }
    }
  }
}

// ---------------- bc = b2 @ T1 + bl1 @ Wl2 + bl2 ----------------
__global__ void k_bias_combine(const float* __restrict__ b2, const float* __restrict__ bl1,
                               const float* __restrict__ bl2, const float* __restrict__ T1,
                               const float* __restrict__ Wl2, float* __restrict__ bc) {
  int j = threadIdx.x;
  if (j >= OUT_CH) return;
  float s = bl2[j];
  for (int k = 0; k < HID; ++k)
    s += b2[k] * T1[k * OUT_CH + j] + bl1[k] * Wl2[k * OUT_CH + j];
  bc[j] = s;
}

extern "C" void kernel_launch(void* const* d_in, const int* in_sizes, int n_in,
                              void* d_out, int out_size, void* d_ws, size_t ws_size,
                              hipStream_t stream) {
  const float* xm  = (const float*)d_in[0];
  const float* xg  = (const float*)d_in[1];
  const int*   ei  = (const int*)d_in[2];
  const float* W1  = (const float*)d_in[3];
  const float* b1  = (const float*)d_in[4];
  const float* W2  = (const float*)d_in[5];
  const float* b2  = (const float*)d_in[6];
  const float* Wl1 = (const float*)d_in[7];
  const float* bl1 = (const float*)d_in[8];
  const float* Wl2 = (const float*)d_in[9];
  const float* bl2 = (const float*)d_in[10];
  float* out = (float*)d_out;

  // ---- workspace layout (floats); peak ~179.4 MB ----
  float* W0 = (float*)d_ws;
  const size_t MB = (size_t)N_GRID * 256;          // 16,680,960
  int*   deg  = (int*)(W0 + MB);
  int*   off  = deg + N_TOT;                       // N_TOT+1
  int*   cur  = off + N_TOT + 1;
  int*   bsum = cur + N_TOT;                       // 512
  int*   csrc = bsum + 512;                        // NE
  float* dinv = (float*)(csrc + NE);               // N_TOT
  float* T1   = dinv + N_TOT;                      // 256*96
  float* Wc   = T1 + HID * OUT_CH;                 // 256*96
  float* bc   = Wc + HID * OUT_CH;                 // 96
  size_t RH = MB + (size_t)4 * N_TOT + 1 + 512 + NE + 2 * HID * OUT_CH + 96;
  RH = (RH + 3) & ~(size_t)3;                      // 16B align
  float* h    = W0 + RH;
  float* h1   = W0 + RH;
  float* agg1 = W0;
  float* agg2 = W0;

  const int* esrc = ei;
  const int* edst = ei + NE;
  dim3 b256(256);
  const int NB_N = (N_TOT + 255) / 256;

  // t1. node features (N_TOT, 96)
  k_concat_transpose<<<dim3((N_TOT + 63) / 64), b256, 0, stream>>>(xg, xm, h);

  // t2. CSR by dst + dinv
  k_zeroi<<<dim3(NB_N), b256, 0, stream>>>(deg, N_TOT);
  k_hist<<<dim3((NE + 255) / 256), b256, 0, stream>>>(edst, deg);
  k_blocksum<<<dim3(NB_N), b256, 0, stream>>>(deg, bsum, N_TOT);
  k_scanbsum<<<dim3(1), dim3(512), 0, stream>>>(bsum, NB_N);
  k_offsets<<<dim3(NB_N), b256, 0, stream>>>(deg, bsum, off, cur, N_TOT);
  k_seti<<<dim3(1), dim3(1), 0, stream>>>(off + N_TOT, NE);
  k_fillcsr<<<dim3((NE + 255) / 256), b256, 0, stream>>>(esrc, edst, cur, csrc);
  k_dinv<<<dim3(NB_N), b256, 0, stream>>>(deg, dinv, N_TOT);

  // t3. agg1 = S @ h   (96 ch, gather)
  k_gather96<<<dim3((N_TOT * 24 + 255) / 256), b256, 0, stream>>>(off, csrc, dinv, h, agg1);

  // t4. h1 = gelu(agg1 @ W1 + b1)   (N_TOT, 256), K=96
  k_gemm<96, 1, false, true><<<dim3(2, (N_TOT + 127) / 128), b256, 0, stream>>>(agg1, W1, b1, h1, N_TOT, HID, HID);

  // t5-t7. combined tail weights: T1 = Wl1@Wl2; Wc = W2@T1; bc = b2@T1 + bl1@Wl2 + bl2
  k_gemm<256, 0, false, false><<<dim3(1, 2), b256, 0, stream>>>(Wl1, Wl2, nullptr, T1, HID, OUT_CH, OUT_CH);
  k_gemm<256, 0, false, false><<<dim3(1, 2), b256, 0, stream>>>(W2, T1, nullptr, Wc, HID, OUT_CH, OUT_CH);
  k_bias_combine<<<dim3(1), dim3(128), 0, stream>>>(b2, bl1, bl2, T1, Wl2, bc);

  // t8. agg2 = S @ h1 for dst < N_GRID   (256 ch, gather)
  k_gather256<<<dim3((N_GRID * 64 + 255) / 256), b256, 0, stream>>>(off, csrc, dinv, h1, agg2);

  // t9. out^T = (agg2 @ Wc + bc)^T   -> (96, N_GRID), K=256
  k_gemm<256, 0, true, true><<<dim3(1, (N_GRID + 127) / 128), b256, 0, stream>>>(agg2, Wc, bc, out, N_GRID, OUT_CH, N_GRID);
}

// Round 8
// 466.703 us; speedup vs baseline: 37.9803x; 37.9803x over previous
//
#include <hip/hip_runtime.h>
#include <math.h>

#define N_GRID 65160
#define N_MESH 40962
#define N_TOT  106122
#define NE     521280
#define IN_CH  96
#define HID    256
#define OUT_CH 96

// ---------------- concat + transpose: (96,N) channel-major -> (N,96) node-major ----------------
__global__ void k_concat_transpose(const float* __restrict__ xg, const float* __restrict__ xm,
                                   float* __restrict__ h) {
  __shared__ float tile[IN_CH][65];
  int base = blockIdx.x * 64;
  int t = threadIdx.x;
#pragma unroll
  for (int it = 0; it < 24; ++it) {
    int lin = t + it * 256;            // 0..6143 over 96x64
    int c  = lin >> 6;
    int n0 = lin & 63;
    int n = base + n0;
    float v = 0.f;
    if (n < N_TOT) {
      v = (n < N_GRID) ? xg[(size_t)c * N_GRID + n]
                       : xm[(size_t)c * N_MESH + (n - N_GRID)];
    }
    tile[c][n0] = v;
  }
  __syncthreads();
#pragma unroll
  for (int it = 0; it < 24; ++it) {
    int lin = t + it * 256;
    int c  = lin % 96;
    int n0 = lin / 96;
    int n = base + n0;
    if (n < N_TOT) h[(size_t)n * IN_CH + c] = tile[c][n0];
  }
}

// ---------------- CSR build ----------------
__global__ void k_zeroi(int* __restrict__ p, int n) {
  int i = blockIdx.x * 256 + threadIdx.x;
  if (i < n) p[i] = 0;
}
__global__ void k_seti(int* __restrict__ p, int v) { *p = v; }

__global__ void k_hist(const int* __restrict__ dst, int* __restrict__ deg) {
  int e = blockIdx.x * 256 + threadIdx.x;
  if (e < NE) atomicAdd(&deg[dst[e]], 1);
}

__global__ void k_blocksum(const int* __restrict__ deg, int* __restrict__ bsum, int n) {
  __shared__ int s[256];
  int i = blockIdx.x * 256 + threadIdx.x;
  s[threadIdx.x] = (i < n) ? deg[i] : 0;
  __syncthreads();
  for (int st = 128; st > 0; st >>= 1) {
    if (threadIdx.x < st) s[threadIdx.x] += s[threadIdx.x + st];
    __syncthreads();
  }
  if (threadIdx.x == 0) bsum[blockIdx.x] = s[0];
}

__global__ void k_scanbsum(int* __restrict__ bsum, int nb) {   // single block, 512 thr
  __shared__ int s[512];
  int t = threadIdx.x;
  int v = (t < nb) ? bsum[t] : 0;
  s[t] = v;
  __syncthreads();
  for (int off = 1; off < 512; off <<= 1) {
    int x = (t >= off) ? s[t - off] : 0;
    __syncthreads();
    s[t] += x;
    __syncthreads();
  }
  if (t < nb) bsum[t] = s[t] - v;   // exclusive
}

__global__ void k_offsets(const int* __restrict__ deg, const int* __restrict__ bsum,
                          int* __restrict__ off, int* __restrict__ cur, int n) {
  __shared__ int s[256];
  int i = blockIdx.x * 256 + threadIdx.x;
  int v = (i < n) ? deg[i] : 0;
  s[threadIdx.x] = v;
  __syncthreads();
  for (int o = 1; o < 256; o <<= 1) {
    int x = (threadIdx.x >= o) ? s[threadIdx.x - o] : 0;
    __syncthreads();
    s[threadIdx.x] += x;
    __syncthreads();
  }
  if (i < n) {
    int e = bsum[blockIdx.x] + s[threadIdx.x] - v;
    off[i] = e;
    cur[i] = e;
  }
}

__global__ void k_fillcsr(const int* __restrict__ src, const int* __restrict__ dst,
                          int* __restrict__ cur, int* __restrict__ csrc) {
  int e = blockIdx.x * 256 + threadIdx.x;
  if (e < NE) {
    int p = atomicAdd(&cur[dst[e]], 1);
    csrc[p] = src[e];
  }
}

__global__ void k_dinv(const int* __restrict__ deg, float* __restrict__ dinv, int n) {
  int i = blockIdx.x * 256 + threadIdx.x;
  if (i < n) dinv[i] = rsqrtf(1.0f + (float)deg[i]);
}

// ---------------- gather aggregation (no atomics), 2-edge unrolled for MLP ----------------
__global__ void k_gather96(const int* __restrict__ off, const int* __restrict__ csrc,
                           const float* __restrict__ dinv, const float* __restrict__ h,
                           float* __restrict__ agg) {
  int i = blockIdx.x * 256 + threadIdx.x;
  if (i >= N_TOT * 24) return;
  int n = i / 24;
  int c4 = (i % 24) << 2;
  float di = dinv[n];
  float4 v = *(const float4*)(h + (size_t)n * 96 + c4);
  float w0 = di * di;
  float4 acc = make_float4(v.x * w0, v.y * w0, v.z * w0, v.w * w0);
  int e0 = off[n], e1 = off[n + 1];
  int e = e0;
  for (; e + 1 < e1; e += 2) {
    int s0 = csrc[e], s1 = csrc[e + 1];
    float wa = dinv[s0] * di, wb = dinv[s1] * di;
    float4 u0 = *(const float4*)(h + (size_t)s0 * 96 + c4);
    float4 u1 = *(const float4*)(h + (size_t)s1 * 96 + c4);
    acc.x += u0.x * wa + u1.x * wb;
    acc.y += u0.y * wa + u1.y * wb;
    acc.z += u0.z * wa + u1.z * wb;
    acc.w += u0.w * wa + u1.w * wb;
  }
  if (e < e1) {
    int s = csrc[e];
    float w = dinv[s] * di;
    float4 u = *(const float4*)(h + (size_t)s * 96 + c4);
    acc.x += u.x * w; acc.y += u.y * w; acc.z += u.z * w; acc.w += u.w * w;
  }
  *(float4*)(agg + (size_t)n * 96 + c4) = acc;
}

__global__ void k_gather256(const int* __restrict__ off, const int* __restrict__ csrc,
                            const float* __restrict__ dinv, const float* __restrict__ h1,
                            float* __restrict__ agg) {
  int i = blockIdx.x * 256 + threadIdx.x;
  if (i >= N_GRID * 64) return;
  int n = i >> 6;
  int c4 = (i & 63) << 2;
  float di = dinv[n];
  float4 v = *(const float4*)(h1 + (size_t)n * 256 + c4);
  float w0 = di * di;
  float4 acc = make_float4(v.x * w0, v.y * w0, v.z * w0, v.w * w0);
  int e0 = off[n], e1 = off[n + 1];
  int e = e0;
  for (; e + 1 < e1; e += 2) {
    int s0 = csrc[e], s1 = csrc[e + 1];
    float wa = dinv[s0] * di, wb = dinv[s1] * di;
    float4 u0 = *(const float4*)(h1 + (size_t)s0 * 256 + c4);
    float4 u1 = *(const float4*)(h1 + (size_t)s1 * 256 + c4);
    acc.x += u0.x * wa + u1.x * wb;
    acc.y += u0.y * wa + u1.y * wb;
    acc.z += u0.z * wa + u1.z * wb;
    acc.w += u0.w * wa + u1.w * wb;
  }
  if (e < e1) {
    int s = csrc[e];
    float w = dinv[s] * di;
    float4 u = *(const float4*)(h1 + (size_t)s * 256 + c4);
    acc.x += u.x * w; acc.y += u.y * w; acc.z += u.z * w; acc.w += u.w * w;
  }
  *(float4*)(agg + (size_t)n * 256 + c4) = acc;
}

// ---------------- fp32 tiled GEMM (round-5 proven config: 114 us, 76 VGPR, no spill) ----------------
// BK=16, single LDS buffer, runtime-K loop (prevents unroll-driven register blowup: rounds 6/7
// fully-unrolled double-buffer versions spilled at both 128 and 256 VGPR caps -> 7-9 ms/GEMM).
// Conflict-free split 4+4 LDS reads; (256,2) cap=128 >= demand 76.
template<int ACT, bool TRANSC, bool BIAS>
__global__ __launch_bounds__(256, 2) void k_gemm(const float* __restrict__ A, const float* __restrict__ W,
                                                 const float* __restrict__ bias, float* __restrict__ C,
                                                 int M, int K, int N, int ldc) {
  constexpr int BM = 128, BN = 128, BK = 16;
  __shared__ float As[BK][BM + 1];   // stride 129: staging writes <=2-way
  __shared__ float Ws[BK][BN + 4];   // stride 132: reads at tx*4 / 64+tx*4 are 2-way (free)
  int t = threadIdx.x;
  int tx = t & 15, ty = t >> 4;
  int bm = blockIdx.y * BM, bn = blockIdx.x * BN;
  float acc[8][8] = {};
  for (int bk = 0; bk < K; bk += BK) {
#pragma unroll
    for (int it = 0; it < 2; ++it) {
      int idx = t + it * 256;              // 0..511 over 128 rows x 4 float4
      int m = idx >> 2, k4 = (idx & 3) << 2;
      float4 v = make_float4(0.f, 0.f, 0.f, 0.f);
      if (bm + m < M) v = *(const float4*)(A + (size_t)(bm + m) * K + bk + k4);
      As[k4 + 0][m] = v.x;
      As[k4 + 1][m] = v.y;
      As[k4 + 2][m] = v.z;
      As[k4 + 3][m] = v.w;
    }
#pragma unroll
    for (int it = 0; it < 2; ++it) {
      int idx = t + it * 256;              // 0..511 over 16 k x 32 float4
      int k = idx >> 5, j4 = (idx & 31) << 2;
      float4 v = make_float4(0.f, 0.f, 0.f, 0.f);
      if (bn + j4 + 3 < N) v = *(const float4*)(W + (size_t)(bk + k) * N + bn + j4);
      *(float4*)&Ws[k][j4] = v;
    }
    __syncthreads();
#pragma unroll
    for (int k = 0; k < BK; ++k) {
      float a[8], w[8];
      *(float4*)&a[0] = *(const float4*)&As[k][ty * 4];
      *(float4*)&a[4] = *(const float4*)&As[k][64 + ty * 4];
      *(float4*)&w[0] = *(const float4*)&Ws[k][tx * 4];
      *(float4*)&w[4] = *(const float4*)&Ws[k][64 + tx * 4];
#pragma unroll
      for (int i = 0; i < 8; ++i)
#pragma unroll
        for (int j = 0; j < 8; ++j)
          acc[i][j] += a[i] * w[j];
    }
    __syncthreads();
  }
  if (!TRANSC) {
#pragma unroll
    for (int i = 0; i < 8; ++i) {
      int gm = bm + ((i < 4) ? ty * 4 + i : 64 + ty * 4 + (i - 4));
      if (gm >= M) continue;
      float v[8];
#pragma unroll
      for (int j = 0; j < 8; ++j) {
        int gj = bn + ((j < 4) ? tx * 4 + j : 64 + tx * 4 + (j - 4));
        float x = acc[i][j];
        if (BIAS && gj < N) x += bias[gj];
        if (ACT) x = 0.5f * x * (1.0f + erff(x * 0.70710678118654752f));
        v[j] = x;
      }
      int c0 = bn + tx * 4, c1 = bn + 64 + tx * 4;
      float* row = C + (size_t)gm * ldc;
      if (c0 + 3 < N) *(float4*)(row + c0) = make_float4(v[0], v[1], v[2], v[3]);
      else { for (int j = 0; j < 4; ++j) if (c0 + j < N) row[c0 + j] = v[j]; }
      if (c1 + 3 < N) *(float4*)(row + c1) = make_float4(v[4], v[5], v[6], v[7]);
      else { for (int j = 0; j < 4; ++j) if (c1 + j < N) row[c1 + j] = v[4 + j]; }
    }
  } else {
#pragma unroll
    for (int j = 0; j < 8; ++j) {
      int gj = bn + ((j < 4) ? tx * 4 + j : 64 + tx * 4 + (j - 4));
      if (gj >= N) continue;
      float b = BIAS ? bias[gj] : 0.f;
      float v[8];
#pragma unroll
      for (int i = 0; i < 8; ++i) {
        float x = acc[i][j] + b;
        if (ACT) x = 0.5f * x * (1.0f + erff(x * 0.70710678118654752f));
        v[i] = x;
      }
      int r0 = bm + ty * 4, r1 = bm + 64 + ty * 4;
      float* col = C + (size_t)gj * ldc;
      if (r0 + 3 < M) *(float4*)(col + r0) = make_float4(v[0], v[1], v[2], v[3]);
      else { for (int i = 0; i < 4; ++i) if (r0 + i < M) col[r0 + i] = v[i]; }
      if (r1 + 3 < M) *(float4*)(col + r1) = make_float4(v[4], v[5], v[6], v[7]);
      else { for (int i = 0; i < 4; ++i) if (r1 + i < M) col[r1 + i] = v[4 + i]; }
    }
  }
}

// ---------------- bc = b2 @ T1 + bl1 @ Wl2 + bl2 ----------------
__global__ void k_bias_combine(const float* __restrict__ b2, const float* __restrict__ bl1,
                               const float* __restrict__ bl2, const float* __restrict__ T1,
                               const float* __restrict__ Wl2, float* __restrict__ bc) {
  int j = threadIdx.x;
  if (j >= OUT_CH) return;
  float s = bl2[j];
  for (int k = 0; k < HID; ++k)
    s += b2[k] * T1[k * OUT_CH + j] + bl1[k] * Wl2[k * OUT_CH + j];
  bc[j] = s;
}

extern "C" void kernel_launch(void* const* d_in, const int* in_sizes, int n_in,
                              void* d_out, int out_size, void* d_ws, size_t ws_size,
                              hipStream_t stream) {
  const float* xm  = (const float*)d_in[0];
  const float* xg  = (const float*)d_in[1];
  const int*   ei  = (const int*)d_in[2];
  const float* W1  = (const float*)d_in[3];
  const float* b1  = (const float*)d_in[4];
  const float* W2  = (const float*)d_in[5];
  const float* b2  = (const float*)d_in[6];
  const float* Wl1 = (const float*)d_in[7];
  const float* bl1 = (const float*)d_in[8];
  const float* Wl2 = (const float*)d_in[9];
  const float* bl2 = (const float*)d_in[10];
  float* out = (float*)d_out;

  // ---- workspace layout (floats); peak ~179.4 MB ----
  float* W0 = (float*)d_ws;
  const size_t MB = (size_t)N_GRID * 256;          // 16,680,960
  int*   deg  = (int*)(W0 + MB);
  int*   off  = deg + N_TOT;                       // N_TOT+1
  int*   cur  = off + N_TOT + 1;
  int*   bsum = cur + N_TOT;                       // 512
  int*   csrc = bsum + 512;                        // NE
  float* dinv = (float*)(csrc + NE);               // N_TOT
  float* T1   = dinv + N_TOT;                      // 256*96
  float* Wc   = T1 + HID * OUT_CH;                 // 256*96
  float* bc   = Wc + HID * OUT_CH;                 // 96
  size_t RH = MB + (size_t)4 * N_TOT + 1 + 512 + NE + 2 * HID * OUT_CH + 96;
  RH = (RH + 3) & ~(size_t)3;                      // 16B align
  float* h    = W0 + RH;
  float* h1   = W0 + RH;
  float* agg1 = W0;
  float* agg2 = W0;

  const int* esrc = ei;
  const int* edst = ei + NE;
  dim3 b256(256);
  const int NB_N = (N_TOT + 255) / 256;

  // t1. node features (N_TOT, 96)
  k_concat_transpose<<<dim3((N_TOT + 63) / 64), b256, 0, stream>>>(xg, xm, h);

  // t2. CSR by dst + dinv
  k_zeroi<<<dim3(NB_N), b256, 0, stream>>>(deg, N_TOT);
  k_hist<<<dim3((NE + 255) / 256), b256, 0, stream>>>(edst, deg);
  k_blocksum<<<dim3(NB_N), b256, 0, stream>>>(deg, bsum, N_TOT);
  k_scanbsum<<<dim3(1), dim3(512), 0, stream>>>(bsum, NB_N);
  k_offsets<<<dim3(NB_N), b256, 0, stream>>>(deg, bsum, off, cur, N_TOT);
  k_seti<<<dim3(1), dim3(1), 0, stream>>>(off + N_TOT, NE);
  k_fillcsr<<<dim3((NE + 255) / 256), b256, 0, stream>>>(esrc, edst, cur, csrc);
  k_dinv<<<dim3(NB_N), b256, 0, stream>>>(deg, dinv, N_TOT);

  // t3. agg1 = S @ h   (96 ch, gather)
  k_gather96<<<dim3((N_TOT * 24 + 255) / 256), b256, 0, stream>>>(off, csrc, dinv, h, agg1);

  // t4. h1 = gelu(agg1 @ W1 + b1)   (N_TOT, 256)
  k_gemm<1, false, true><<<dim3(2, (N_TOT + 127) / 128), b256, 0, stream>>>(agg1, W1, b1, h1, N_TOT, IN_CH, HID, HID);

  // t5-t7. combined tail weights: T1 = Wl1@Wl2; Wc = W2@T1; bc = b2@T1 + bl1@Wl2 + bl2
  k_gemm<0, false, false><<<dim3(1, 2), b256, 0, stream>>>(Wl1, Wl2, nullptr, T1, HID, HID, OUT_CH, OUT_CH);
  k_gemm<0, false, false><<<dim3(1, 2), b256, 0, stream>>>(W2, T1, nullptr, Wc, HID, HID, OUT_CH, OUT_CH);
  k_bias_combine<<<dim3(1), dim3(128), 0, stream>>>(b2, bl1, bl2, T1, Wl2, bc);

  // t8. agg2 = S @ h1 for dst < N_GRID   (256 ch, gather)
  k_gather256<<<dim3((N_GRID * 64 + 255) / 256), b256, 0, stream>>>(off, csrc, dinv, h1, agg2);

  // t9. out^T = (agg2 @ Wc + bc)^T   -> (96, N_GRID)
  k_gemm<0, true, true><<<dim3(1, (N_GRID + 127) / 128), b256, 0, stream>>>(agg2, Wc, bc, out, N_GRID, HID, OUT_CH, N_GRID);
}